// Round 2
// baseline (2959.969 us; speedup 1.0000x reference)
//
#include <hip/hip_runtime.h>
#include <hip/hip_bf16.h>
#include <math.h>

// RWKV-7 Tmix forward, MI355X/gfx950.
// B=2 T=1024 C=2048 H=32 N=64. Outputs: xo [B,T,C], x[:,-1] [B,C], S_final [B,H,N,N].
// Workspace: 6 fp32 [BT,C] + small LoRA bufs + 5 bf16 [2048,2048] = ~146 MB (was 305 MB -> crash).

#define B_ 2
#define T_ 1024
#define C_ 2048
#define H_ 32
#define BT_ (B_*T_)
#define BTC_ ((size_t)BT_*C_)
#define CC_ ((size_t)C_*C_)

typedef __bf16 bf16x8 __attribute__((ext_vector_type(8)));
typedef float f32x4 __attribute__((ext_vector_type(4)));

__device__ __forceinline__ float wave64_sum(float v){
#pragma unroll
  for (int d = 1; d < 64; d <<= 1) v += __shfl_xor(v, d, 64);
  return v;
}

// ---------------- fp32 -> bf16 convert ----------------
__global__ __launch_bounds__(256) void f2bf_kernel(const float* __restrict__ in,
                                                   __hip_bfloat16* __restrict__ out, size_t n){
  size_t i = (size_t)blockIdx.x*256 + threadIdx.x;
  if (i < n) out[i] = __float2bfloat16(in[i]);
}

// ---------------- token shift ----------------
__global__ __launch_bounds__(256) void shift_kernel(const float* __restrict__ x,
                                                    const float* __restrict__ shift,
                                                    const float* __restrict__ maa_x,
                                                    float* __restrict__ xx, float* __restrict__ xmx){
  size_t idx = (size_t)blockIdx.x*256 + threadIdx.x;  // over BTC
  int c = (int)(idx % C_);
  size_t bt = idx / C_;
  int t = (int)(bt % T_);
  int b = (int)(bt / T_);
  float xv = x[idx];
  float prev = (t == 0) ? shift[(size_t)b*C_ + c] : x[idx - C_];
  float d = prev - xv;
  xx[idx] = d;
  xmx[idx] = xv + d * maa_x[c];
}

// ---------------- fp32 A[M,K] @ W[K,N], small N, optional tanh ----------------
__global__ __launch_bounds__(256) void mm_sn(const float* __restrict__ A, const float* __restrict__ W,
                                             float* __restrict__ out, int K, int Nn, int doTanh){
  const int rpb = 256 / Nn;
  const int c = threadIdx.x % Nn;
  const int i = blockIdx.x * rpb + threadIdx.x / Nn;
  const float* Ar = A + (size_t)i * K;
  const float* Wc = W + c;
  float acc = 0.f;
  for (int kk = 0; kk < K; kk += 4){
    float4 av = *(const float4*)(Ar + kk);
    acc += av.x * Wc[(size_t)kk*Nn];
    acc += av.y * Wc[(size_t)(kk+1)*Nn];
    acc += av.z * Wc[(size_t)(kk+2)*Nn];
    acc += av.w * Wc[(size_t)(kk+3)*Nn];
  }
  out[(size_t)i*Nn + c] = doTanh ? tanhf(acc) : acc;
}

// ---------------- bf16 A[M,K] @ fp32 W[K,N], small N, optional tanh ----------------
__global__ __launch_bounds__(256) void mm_sn_h(const __hip_bfloat16* __restrict__ A, const float* __restrict__ W,
                                               float* __restrict__ out, int K, int Nn, int doTanh){
  const int rpb = 256 / Nn;
  const int c = threadIdx.x % Nn;
  const int i = blockIdx.x * rpb + threadIdx.x / Nn;
  const unsigned short* Ar = (const unsigned short*)(A + (size_t)i * K);
  const float* Wc = W + c;
  float acc = 0.f;
  for (int kk = 0; kk < K; kk += 8){
    uint4 av = *(const uint4*)(Ar + kk);
    unsigned int u[4] = {av.x, av.y, av.z, av.w};
#pragma unroll
    for (int q = 0; q < 4; q++){
      float f0 = __uint_as_float(u[q] << 16);
      float f1 = __uint_as_float(u[q] & 0xffff0000u);
      acc += f0 * Wc[(size_t)(kk+2*q)*Nn];
      acc += f1 * Wc[(size_t)(kk+2*q+1)*Nn];
    }
  }
  out[(size_t)i*Nn + c] = doTanh ? tanhf(acc) : acc;
}

// ---------------- g = g1[BT,128] @ gw2[128,C] -> bf16 ----------------
__global__ __launch_bounds__(256) void mm_sk_g(const float* __restrict__ A, const float* __restrict__ W,
                                               __hip_bfloat16* __restrict__ out, int K){
  const int j = blockIdx.y*256 + threadIdx.x;
  const int i0 = blockIdx.x*8;
  float acc[8] = {0,0,0,0,0,0,0,0};
  for (int k = 0; k < K; k++){
    float wv = W[(size_t)k*C_ + j];
#pragma unroll
    for (int r = 0; r < 8; r++) acc[r] += A[(size_t)(i0+r)*K + k] * wv;
  }
#pragma unroll
  for (int r = 0; r < 8; r++) out[(size_t)(i0+r)*C_ + j] = __float2bfloat16(acc[r]);
}

// ---------------- maa einsum + mix -> bf16 xrg/xwa/xk/xv ----------------
__global__ __launch_bounds__(256) void mix_kernel(
    const float* __restrict__ m1, const float* __restrict__ w2,
    const float* __restrict__ x, const float* __restrict__ xx,
    const float* __restrict__ maa_rg, const float* __restrict__ maa_wa,
    const float* __restrict__ maa_k, const float* __restrict__ maa_v,
    __hip_bfloat16* __restrict__ xrg_h, __hip_bfloat16* __restrict__ xwa_h,
    __hip_bfloat16* __restrict__ xk_h, __hip_bfloat16* __restrict__ xv_h)
{
  const int j = blockIdx.y*256 + threadIdx.x;
  const int i0 = blockIdx.x*8;
  float acc[4][8] = {};
#pragma unroll
  for (int f = 0; f < 4; f++){
    for (int d = 0; d < 32; d++){
      float wv = w2[((size_t)f*32 + d)*C_ + j];
#pragma unroll
      for (int r = 0; r < 8; r++)
        acc[f][r] += m1[(size_t)(i0+r)*128 + f*32 + d] * wv;
    }
  }
  float mrg_ = maa_rg[j], mwa_ = maa_wa[j], mk_ = maa_k[j], mv_ = maa_v[j];
#pragma unroll
  for (int r = 0; r < 8; r++){
    size_t idx = (size_t)(i0+r)*C_ + j;
    float xval = x[idx], xxv = xx[idx];
    xrg_h[idx] = __float2bfloat16(xval + xxv*(mrg_ + acc[0][r]));
    xwa_h[idx] = __float2bfloat16(xval + xxv*(mwa_ + acc[1][r]));
    xk_h[idx]  = __float2bfloat16(xval + xxv*(mk_  + acc[2][r]));
    xv_h[idx]  = __float2bfloat16(xval + xxv*(mv_  + acc[3][r]));
  }
}

// ---------------- bf16 MFMA GEMM: C[M,N] = A[M,K] * B[N,K]^T (fp32 out) ----------------
__global__ __launch_bounds__(256) void gemm_bt(const __hip_bfloat16* __restrict__ Ah,
                                               const __hip_bfloat16* __restrict__ Bh,
                                               float* __restrict__ Cc, int M, int Nn, int K){
  __shared__ __bf16 As[128*40];   // pad stride 40 bf16 = 80 B (16B-aligned, 2-way banks = free)
  __shared__ __bf16 Bs[128*40];
  const int tid = threadIdx.x;
  const int bm = blockIdx.x*128, bn = blockIdx.y*128;
  const int wid = tid >> 6, lane = tid & 63;
  const int wr = (wid >> 1)*64, wc = (wid & 1)*64;
  const int fr = lane & 15, kg = lane >> 4;
  const int srow = tid >> 2, sk = (tid & 3)*8;
  f32x4 acc[4][4] = {};
  for (int kt = 0; kt < K; kt += 32){
    __syncthreads();
    uint4 a0 = *(const uint4*)(Ah + (size_t)(bm+srow)*K + kt + sk);
    uint4 a1 = *(const uint4*)(Ah + (size_t)(bm+srow+64)*K + kt + sk);
    uint4 b0 = *(const uint4*)(Bh + (size_t)(bn+srow)*K + kt + sk);
    uint4 b1 = *(const uint4*)(Bh + (size_t)(bn+srow+64)*K + kt + sk);
    *(uint4*)(As + srow*40 + sk)      = a0;
    *(uint4*)(As + (srow+64)*40 + sk) = a1;
    *(uint4*)(Bs + srow*40 + sk)      = b0;
    *(uint4*)(Bs + (srow+64)*40 + sk) = b1;
    __syncthreads();
    bf16x8 af[4], bfr[4];
#pragma unroll
    for (int i = 0; i < 4; i++){
      af[i]  = *(const bf16x8*)(As + (wr + i*16 + fr)*40 + kg*8);
      bfr[i] = *(const bf16x8*)(Bs + (wc + i*16 + fr)*40 + kg*8);
    }
#pragma unroll
    for (int mi = 0; mi < 4; mi++)
#pragma unroll
      for (int ni = 0; ni < 4; ni++)
        acc[mi][ni] = __builtin_amdgcn_mfma_f32_16x16x32_bf16(af[mi], bfr[ni], acc[mi][ni], 0, 0, 0);
  }
  const int orow0 = bm + wr + kg*4;
  const int ocol0 = bn + wc + fr;
#pragma unroll
  for (int mi = 0; mi < 4; mi++)
#pragma unroll
    for (int ni = 0; ni < 4; ni++)
#pragma unroll
      for (int j = 0; j < 4; j++)
        Cc[(size_t)(orow0 + mi*16 + j)*Nn + ocol0 + ni*16] = acc[mi][ni][j];
}

// ---------------- fused LoRA stage-2 + decay/gates elementwise ----------------
__global__ __launch_bounds__(256) void lora2_kernel(
    const float* __restrict__ d1, const float* __restrict__ a1, const float* __restrict__ ma1,
    const float* __restrict__ mk1, const float* __restrict__ kk1,
    const float* __restrict__ dw2, const float* __restrict__ aw2, const float* __restrict__ maw2,
    const float* __restrict__ mkw2, const float* __restrict__ kkw2,
    const float* __restrict__ td, const float* __restrict__ aaaaa,
    const float* __restrict__ misc_a, const float* __restrict__ misc_k,
    float* __restrict__ k0,                    // in: raw k  out: final k
    float* __restrict__ a_out, float* __restrict__ ew_out, float* __restrict__ kk0_out)
{
  const int j = blockIdx.y*256 + threadIdx.x;
  const int i0 = blockIdx.x*8;
  float accW[8] = {}, accA[8] = {}, accMA[8] = {}, accMK[8] = {}, accKK[8] = {};
  for (int k = 0; k < 64; k++){
    float wv = dw2[(size_t)k*C_ + j];
#pragma unroll
    for (int r = 0; r < 8; r++) accW[r] += d1[(size_t)(i0+r)*64 + k] * wv;
  }
  for (int k = 0; k < 16; k++){
    float w_a  = aw2[(size_t)k*C_ + j];
    float w_ma = maw2[(size_t)k*C_ + j];
    float w_mk = mkw2[(size_t)k*C_ + j];
    float w_kk = kkw2[(size_t)k*C_ + j];
#pragma unroll
    for (int r = 0; r < 8; r++){
      accA[r]  += a1[(size_t)(i0+r)*16 + k] * w_a;
      accMA[r] += ma1[(size_t)(i0+r)*16 + k] * w_ma;
      accMK[r] += mk1[(size_t)(i0+r)*16 + k] * w_mk;
      accKK[r] += kk1[(size_t)(i0+r)*16 + k] * w_kk;
    }
  }
  float tdv = td[j], aav = aaaaa[j], mav = misc_a[j], mkv = misc_k[j];
#pragma unroll
  for (int r = 0; r < 8; r++){
    size_t idx = (size_t)(i0+r)*C_ + j;
    float u  = tdv + accW[r];
    float w  = -log1pf(expf(-u)) - 0.5f;               // -softplus(-u) - 0.5
    float a  = 1.f/(1.f + expf(-(aav + accA[r])));
    float ma = 1.f/(1.f + expf(-(mav + accMA[r])));
    float mk = 1.f/(1.f + expf(-(mkv + accMK[r])));
    float kv = k0[idx];
    kk0_out[idx] = kv + accKK[r];
    float kn = kv * (ma + a*(1.f - ma)) * expf(fminf(w*mk, 0.f));
    k0[idx] = kn;
    a_out[idx] = a;
    ew_out[idx] = expf(w);
  }
}

// ---------------- kk normalize per head + b = kk*a (in-place) ----------------
__global__ __launch_bounds__(256) void kknorm_kernel(float* __restrict__ kk0, float* __restrict__ a_bs){
  const size_t grp = (size_t)blockIdx.x*4 + (threadIdx.x >> 6);
  const int lane = threadIdx.x & 63;
  const size_t idx = grp*64 + lane;
  float kv = kk0[idx];
  float ss = wave64_sum(kv*kv);
  float nrm = fmaxf(sqrtf(ss), 1e-12f);
  float kkn = kv / nrm;
  kk0[idx] = kkn;
  a_bs[idx] = kkn * a_bs[idx];
}

// ---------------- RWKV-7 recurrence: 64 blocks (b,h) x 256 threads ----------------
__global__ __launch_bounds__(256) void rec_kernel(
    const float* __restrict__ rr, const float* __restrict__ kx,
    const float* __restrict__ vx, const float* __restrict__ ew,
    const float* __restrict__ kkv, const float* __restrict__ bsv,
    const float* __restrict__ s0, float* __restrict__ o, float* __restrict__ sT)
{
  const int bh = blockIdx.x;
  const int b = bh >> 5, h = bh & 31;
  const int wid = threadIdx.x >> 6, lane = threadIdx.x & 63;
  const int v = wid*16 + (lane & 15);
  const int kq = lane >> 4;
  float S[16];
  {
    const float* p = s0 + ((size_t)bh*64 + kq*16)*64 + v;
#pragma unroll
    for (int i = 0; i < 16; i++) S[i] = p[(size_t)i*64];
  }
  const size_t base = (size_t)b*T_*(H_*64) + (size_t)h*64;
  for (int t = 0; t < T_; t++){
    const size_t off = base + (size_t)t*(H_*64);
    const size_t ko = off + kq*16;
    float aarr[16], earr[16], karr[16], barr[16], rarr[16];
#pragma unroll
    for (int i = 0; i < 16; i++){
      aarr[i] = kkv[ko+i]; earr[i] = ew[ko+i]; karr[i] = kx[ko+i];
      barr[i] = bsv[ko+i]; rarr[i] = rr[ko+i];
    }
    float vt = vx[off + v];
    float sap = 0.f;
#pragma unroll
    for (int i = 0; i < 16; i++) sap += aarr[i]*S[i];
    sap += __shfl_xor(sap, 16, 64);
    sap += __shfl_xor(sap, 32, 64);
    const float sa = -sap;            // a_t = -kk
    float op = 0.f;
#pragma unroll
    for (int i = 0; i < 16; i++){
      S[i] = S[i]*earr[i] + karr[i]*vt + barr[i]*sa;
      op += rarr[i]*S[i];
    }
    op += __shfl_xor(op, 16, 64);
    op += __shfl_xor(op, 32, 64);
    if (kq == 0) o[off + v] = op;
  }
  float* p = sT + ((size_t)bh*64 + kq*16)*64 + v;
#pragma unroll
  for (int i = 0; i < 16; i++) p[(size_t)i*64] = S[i];
}

// ---------------- GroupNorm + faaaa term + *g -> z (bf16) ----------------
__global__ __launch_bounds__(256) void post_kernel(
    const float* __restrict__ o, const float* __restrict__ r, const float* __restrict__ k,
    const float* __restrict__ v, const __hip_bfloat16* __restrict__ g,
    const float* __restrict__ lnw, const float* __restrict__ lnb,
    const float* __restrict__ faaaa, __hip_bfloat16* __restrict__ z_h)
{
  const size_t grp = (size_t)blockIdx.x*4 + (threadIdx.x >> 6);
  const int lane = threadIdx.x & 63;
  const int h = (int)(grp & (H_-1));
  const size_t idx = grp*64 + lane;
  const int ci = h*64 + lane;
  float y = o[idx];
  float mu = wave64_sum(y) * (1.f/64.f);
  float d = y - mu;
  float var = wave64_sum(d*d) * (1.f/64.f);
  float yn = d * rsqrtf(var + 64e-5f) * lnw[ci] + lnb[ci];
  float s = wave64_sum(r[idx]*k[idx]*faaaa[ci]);
  float xo = yn + s*v[idx];
  z_h[idx] = __float2bfloat16(xo * __bfloat162float(g[idx]));
}

// ---------------- x[:, -1] ----------------
__global__ __launch_bounds__(256) void lastx_kernel(const float* __restrict__ x, float* __restrict__ out1){
  int idx = blockIdx.x*256 + threadIdx.x;   // B*C
  int b = idx / C_, c = idx % C_;
  out1[idx] = x[((size_t)b*T_ + (T_-1))*C_ + c];
}

extern "C" void kernel_launch(void* const* d_in, const int* in_sizes, int n_in,
                              void* d_out, int out_size, void* d_ws, size_t ws_size,
                              hipStream_t stream){
  (void)in_sizes; (void)n_in; (void)out_size;
  const float* x      = (const float*)d_in[0];
  const float* shift  = (const float*)d_in[1];
  const float* wkv0   = (const float*)d_in[2];
  const float* maa_x  = (const float*)d_in[3];
  const float* maa_rg = (const float*)d_in[4];
  const float* maa_wa = (const float*)d_in[5];
  const float* maa_k  = (const float*)d_in[6];
  const float* maa_v  = (const float*)d_in[7];
  const float* maa_w1 = (const float*)d_in[8];
  const float* maa_w2 = (const float*)d_in[9];
  const float* tdecay = (const float*)d_in[10];
  const float* dw1    = (const float*)d_in[11];
  const float* dw2    = (const float*)d_in[12];
  const float* faaaa  = (const float*)d_in[13];
  const float* aaaaa  = (const float*)d_in[14];
  const float* aw1    = (const float*)d_in[15];
  const float* aw2    = (const float*)d_in[16];
  const float* kkw1   = (const float*)d_in[17];
  const float* kkw2   = (const float*)d_in[18];
  const float* gw1    = (const float*)d_in[19];
  const float* gw2    = (const float*)d_in[20];
  const float* maw1   = (const float*)d_in[21];
  const float* maw2   = (const float*)d_in[22];
  const float* misc_a = (const float*)d_in[23];
  const float* mkw1   = (const float*)d_in[24];
  const float* mkw2   = (const float*)d_in[25];
  const float* misc_k = (const float*)d_in[26];
  const float* Wr     = (const float*)d_in[27];
  const float* Wk     = (const float*)d_in[28];
  const float* Wv     = (const float*)d_in[29];
  const float* Wo     = (const float*)d_in[30];
  const float* lnw    = (const float*)d_in[31];
  const float* lnb    = (const float*)d_in[32];

  float* out0 = (float*)d_out;                 // [B,T,C]  (also holds o pre-epilogue)
  float* out1 = out0 + BTC_;                   // [B,C]
  float* outS = out1 + (size_t)B_*C_;          // [B,H,N,N]

  // ---- workspace layout (floats) ----
  // [0..6*BTC): rbuf kbuf vbuf abuf ewbuf kkbuf   (xx=abuf, xmx=ewbuf early aliases)
  // [small]:    m1(BT*128) d1(BT*64) g1(BT*128) a1 kk1 ma1 mk1 (BT*16 each)
  // [bf16]:     xrg_h | xwa_h(->g_h) | xk_h | xv_h(->z_h) | Wb   (CC_ bf16 each)
  const size_t SMALL = (size_t)BT_*(128+64+128+16*4);
  const size_t NEEDED = (6*BTC_ + SMALL)*4 + 5*CC_*2;
  if (ws_size < NEEDED) return;   // diagnostic: clean fail instead of OOB fault

  float* ws = (float*)d_ws;
  float* rbuf  = ws;
  float* kbuf  = ws + 1*BTC_;
  float* vbuf  = ws + 2*BTC_;
  float* abuf  = ws + 3*BTC_;   // a -> b_s ; early alias: xx
  float* ewbuf = ws + 4*BTC_;   // exp(w)   ; early alias: xmx
  float* kkbuf = ws + 5*BTC_;   // kk0 -> kk
  float* xx  = abuf;
  float* xmx = ewbuf;
  float* m1  = ws + 6*BTC_;
  float* d1  = m1  + (size_t)BT_*128;
  float* g1  = d1  + (size_t)BT_*64;
  float* a1  = g1  + (size_t)BT_*128;
  float* kk1 = a1  + (size_t)BT_*16;
  float* ma1 = kk1 + (size_t)BT_*16;
  float* mk1 = ma1 + (size_t)BT_*16;
  __hip_bfloat16* hb = (__hip_bfloat16*)(mk1 + (size_t)BT_*16);
  __hip_bfloat16* xrg_h = hb;
  __hip_bfloat16* xwa_h = hb + 1*CC_;
  __hip_bfloat16* xk_h  = hb + 2*CC_;
  __hip_bfloat16* xv_h  = hb + 3*CC_;
  __hip_bfloat16* Wb    = hb + 4*CC_;
  __hip_bfloat16* g_h   = xwa_h;  // xwa_h dead after LoRA stage-1
  __hip_bfloat16* z_h   = xv_h;   // xv_h dead after v GEMM

  dim3 blk(256);

  // token shift + maa stage 1 + mix
  shift_kernel<<<(int)(BTC_/256), blk, 0, stream>>>(x, shift, maa_x, xx, xmx);
  mm_sn<<<BT_/2, blk, 0, stream>>>(xmx, maa_w1, m1, C_, 128, 1);
  mix_kernel<<<dim3(BT_/8, C_/256), blk, 0, stream>>>(m1, maa_w2, x, xx, maa_rg, maa_wa, maa_k, maa_v,
                                                      xrg_h, xwa_h, xk_h, xv_h);
  // LoRA stage 1 (bf16 activations)
  mm_sn_h<<<BT_/4,  blk, 0, stream>>>(xwa_h, dw1,  d1,  C_, 64, 1);
  mm_sn_h<<<BT_/2,  blk, 0, stream>>>(xrg_h, gw1,  g1,  C_, 128, 1);
  mm_sn_h<<<BT_/16, blk, 0, stream>>>(xwa_h, aw1,  a1,  C_, 16, 0);
  mm_sn_h<<<BT_/16, blk, 0, stream>>>(xk_h,  kkw1, kk1, C_, 16, 1);
  mm_sn_h<<<BT_/16, blk, 0, stream>>>(xwa_h, maw1, ma1, C_, 16, 0);
  mm_sn_h<<<BT_/16, blk, 0, stream>>>(xk_h,  mkw1, mk1, C_, 16, 0);
  // g (overwrites xwa_h slot - safe after LoRA1)
  mm_sk_g<<<dim3(BT_/8, C_/256), blk, 0, stream>>>(g1, gw2, g_h, 128);

  // big GEMMs with sequential weight conversion into shared Wb
  f2bf_kernel<<<(int)(CC_/256), blk, 0, stream>>>(Wr, Wb, CC_);
  gemm_bt<<<dim3(BT_/128, C_/128), blk, 0, stream>>>(xrg_h, Wb, rbuf, BT_, C_, C_);
  f2bf_kernel<<<(int)(CC_/256), blk, 0, stream>>>(Wk, Wb, CC_);
  gemm_bt<<<dim3(BT_/128, C_/128), blk, 0, stream>>>(xk_h,  Wb, kbuf, BT_, C_, C_);
  f2bf_kernel<<<(int)(CC_/256), blk, 0, stream>>>(Wv, Wb, CC_);
  gemm_bt<<<dim3(BT_/128, C_/128), blk, 0, stream>>>(xv_h,  Wb, vbuf, BT_, C_, C_);

  // LoRA stage 2 fused + elementwise, then kk normalize
  lora2_kernel<<<dim3(BT_/8, C_/256), blk, 0, stream>>>(d1, a1, ma1, mk1, kk1,
                                                        dw2, aw2, maw2, mkw2, kkw2,
                                                        tdecay, aaaaa, misc_a, misc_k,
                                                        kbuf, abuf, ewbuf, kkbuf);
  kknorm_kernel<<<BT_*H_/4, blk, 0, stream>>>(kkbuf, abuf);

  // recurrence (o written into out0, overwritten by final GEMM later)
  rec_kernel<<<B_*H_, blk, 0, stream>>>(rbuf, kbuf, vbuf, ewbuf, kkbuf, abuf, wkv0, out0, outS);

  // groupnorm + faaaa + gate -> z_h (bf16), final GEMM, last-x copy
  post_kernel<<<BT_*H_/4, blk, 0, stream>>>(out0, rbuf, kbuf, vbuf, g_h, lnw, lnb, faaaa, z_h);
  f2bf_kernel<<<(int)(CC_/256), blk, 0, stream>>>(Wo, Wb, CC_);
  gemm_bt<<<dim3(BT_/128, C_/128), blk, 0, stream>>>(z_h, Wb, out0, BT_, C_, C_);
  lastx_kernel<<<(B_*C_)/256, blk, 0, stream>>>(x, out1);
}

// Round 3
// 2072.810 us; speedup vs baseline: 1.4280x; 1.4280x over previous
//
#include <hip/hip_runtime.h>
#include <hip/hip_bf16.h>
#include <math.h>

// RWKV-7 Tmix forward, MI355X/gfx950.
// B=2 T=1024 C=2048 H=32 N=64. Outputs: xo [B,T,C], x[:,-1] [B,C], S_final [B,H,N,N].
// Workspace: 6 fp32 [BT,C] + small LoRA bufs + 5 bf16 [2048,2048] = ~146 MB.

#define B_ 2
#define T_ 1024
#define C_ 2048
#define H_ 32
#define BT_ (B_*T_)
#define BTC_ ((size_t)BT_*C_)
#define CC_ ((size_t)C_*C_)

typedef __bf16 bf16x8 __attribute__((ext_vector_type(8)));
typedef float f32x4 __attribute__((ext_vector_type(4)));

__device__ __forceinline__ float wave64_sum(float v){
#pragma unroll
  for (int d = 1; d < 64; d <<= 1) v += __shfl_xor(v, d, 64);
  return v;
}

// ---------------- fp32 -> bf16 convert ----------------
__global__ __launch_bounds__(256) void f2bf_kernel(const float* __restrict__ in,
                                                   __hip_bfloat16* __restrict__ out, size_t n){
  size_t i = (size_t)blockIdx.x*256 + threadIdx.x;
  if (i < n) out[i] = __float2bfloat16(in[i]);
}

// ---------------- token shift ----------------
__global__ __launch_bounds__(256) void shift_kernel(const float* __restrict__ x,
                                                    const float* __restrict__ shift,
                                                    const float* __restrict__ maa_x,
                                                    float* __restrict__ xx, float* __restrict__ xmx){
  size_t idx = (size_t)blockIdx.x*256 + threadIdx.x;  // over BTC
  int c = (int)(idx % C_);
  size_t bt = idx / C_;
  int t = (int)(bt % T_);
  int b = (int)(bt / T_);
  float xv = x[idx];
  float prev = (t == 0) ? shift[(size_t)b*C_ + c] : x[idx - C_];
  float d = prev - xv;
  xx[idx] = d;
  xmx[idx] = xv + d * maa_x[c];
}

// ---------------- fp32 A[M,K] @ W[K,N], small N, optional tanh ----------------
__global__ __launch_bounds__(256) void mm_sn(const float* __restrict__ A, const float* __restrict__ W,
                                             float* __restrict__ out, int K, int Nn, int doTanh){
  const int rpb = 256 / Nn;
  const int c = threadIdx.x % Nn;
  const int i = blockIdx.x * rpb + threadIdx.x / Nn;
  const float* Ar = A + (size_t)i * K;
  const float* Wc = W + c;
  float acc = 0.f;
  for (int kk = 0; kk < K; kk += 4){
    float4 av = *(const float4*)(Ar + kk);
    acc += av.x * Wc[(size_t)kk*Nn];
    acc += av.y * Wc[(size_t)(kk+1)*Nn];
    acc += av.z * Wc[(size_t)(kk+2)*Nn];
    acc += av.w * Wc[(size_t)(kk+3)*Nn];
  }
  out[(size_t)i*Nn + c] = doTanh ? tanhf(acc) : acc;
}

// ---------------- bf16 A[M,K] @ fp32 W[K,N], small N, optional tanh ----------------
__global__ __launch_bounds__(256) void mm_sn_h(const __hip_bfloat16* __restrict__ A, const float* __restrict__ W,
                                               float* __restrict__ out, int K, int Nn, int doTanh){
  const int rpb = 256 / Nn;
  const int c = threadIdx.x % Nn;
  const int i = blockIdx.x * rpb + threadIdx.x / Nn;
  const unsigned short* Ar = (const unsigned short*)(A + (size_t)i * K);
  const float* Wc = W + c;
  float acc = 0.f;
  for (int kk = 0; kk < K; kk += 8){
    uint4 av = *(const uint4*)(Ar + kk);
    unsigned int u[4] = {av.x, av.y, av.z, av.w};
#pragma unroll
    for (int q = 0; q < 4; q++){
      float f0 = __uint_as_float(u[q] << 16);
      float f1 = __uint_as_float(u[q] & 0xffff0000u);
      acc += f0 * Wc[(size_t)(kk+2*q)*Nn];
      acc += f1 * Wc[(size_t)(kk+2*q+1)*Nn];
    }
  }
  out[(size_t)i*Nn + c] = doTanh ? tanhf(acc) : acc;
}

// ---------------- g = g1[BT,128] @ gw2[128,C] -> bf16 ----------------
__global__ __launch_bounds__(256) void mm_sk_g(const float* __restrict__ A, const float* __restrict__ W,
                                               __hip_bfloat16* __restrict__ out, int K){
  const int j = blockIdx.y*256 + threadIdx.x;
  const int i0 = blockIdx.x*8;
  float acc[8] = {0,0,0,0,0,0,0,0};
  for (int k = 0; k < K; k++){
    float wv = W[(size_t)k*C_ + j];
#pragma unroll
    for (int r = 0; r < 8; r++) acc[r] += A[(size_t)(i0+r)*K + k] * wv;
  }
#pragma unroll
  for (int r = 0; r < 8; r++) out[(size_t)(i0+r)*C_ + j] = __float2bfloat16(acc[r]);
}

// ---------------- maa einsum + mix -> bf16 xrg/xwa/xk/xv ----------------
__global__ __launch_bounds__(256) void mix_kernel(
    const float* __restrict__ m1, const float* __restrict__ w2,
    const float* __restrict__ x, const float* __restrict__ xx,
    const float* __restrict__ maa_rg, const float* __restrict__ maa_wa,
    const float* __restrict__ maa_k, const float* __restrict__ maa_v,
    __hip_bfloat16* __restrict__ xrg_h, __hip_bfloat16* __restrict__ xwa_h,
    __hip_bfloat16* __restrict__ xk_h, __hip_bfloat16* __restrict__ xv_h)
{
  const int j = blockIdx.y*256 + threadIdx.x;
  const int i0 = blockIdx.x*8;
  float acc[4][8] = {};
#pragma unroll
  for (int f = 0; f < 4; f++){
    for (int d = 0; d < 32; d++){
      float wv = w2[((size_t)f*32 + d)*C_ + j];
#pragma unroll
      for (int r = 0; r < 8; r++)
        acc[f][r] += m1[(size_t)(i0+r)*128 + f*32 + d] * wv;
    }
  }
  float mrg_ = maa_rg[j], mwa_ = maa_wa[j], mk_ = maa_k[j], mv_ = maa_v[j];
#pragma unroll
  for (int r = 0; r < 8; r++){
    size_t idx = (size_t)(i0+r)*C_ + j;
    float xval = x[idx], xxv = xx[idx];
    xrg_h[idx] = __float2bfloat16(xval + xxv*(mrg_ + acc[0][r]));
    xwa_h[idx] = __float2bfloat16(xval + xxv*(mwa_ + acc[1][r]));
    xk_h[idx]  = __float2bfloat16(xval + xxv*(mk_  + acc[2][r]));
    xv_h[idx]  = __float2bfloat16(xval + xxv*(mv_  + acc[3][r]));
  }
}

// ---------------- bf16 MFMA GEMM: C[M,N] = A[M,K] * B[N,K]^T (fp32 out) ----------------
__global__ __launch_bounds__(256) void gemm_bt(const __hip_bfloat16* __restrict__ Ah,
                                               const __hip_bfloat16* __restrict__ Bh,
                                               float* __restrict__ Cc, int M, int Nn, int K){
  __shared__ __bf16 As[128*40];   // pad stride 40 bf16 = 80 B (16B-aligned, 2-way banks = free)
  __shared__ __bf16 Bs[128*40];
  const int tid = threadIdx.x;
  const int bm = blockIdx.x*128, bn = blockIdx.y*128;
  const int wid = tid >> 6, lane = tid & 63;
  const int wr = (wid >> 1)*64, wc = (wid & 1)*64;
  const int fr = lane & 15, kg = lane >> 4;
  const int srow = tid >> 2, sk = (tid & 3)*8;
  f32x4 acc[4][4] = {};
  for (int kt = 0; kt < K; kt += 32){
    __syncthreads();
    uint4 a0 = *(const uint4*)(Ah + (size_t)(bm+srow)*K + kt + sk);
    uint4 a1 = *(const uint4*)(Ah + (size_t)(bm+srow+64)*K + kt + sk);
    uint4 b0 = *(const uint4*)(Bh + (size_t)(bn+srow)*K + kt + sk);
    uint4 b1 = *(const uint4*)(Bh + (size_t)(bn+srow+64)*K + kt + sk);
    *(uint4*)(As + srow*40 + sk)      = a0;
    *(uint4*)(As + (srow+64)*40 + sk) = a1;
    *(uint4*)(Bs + srow*40 + sk)      = b0;
    *(uint4*)(Bs + (srow+64)*40 + sk) = b1;
    __syncthreads();
    bf16x8 af[4], bfr[4];
#pragma unroll
    for (int i = 0; i < 4; i++){
      af[i]  = *(const bf16x8*)(As + (wr + i*16 + fr)*40 + kg*8);
      bfr[i] = *(const bf16x8*)(Bs + (wc + i*16 + fr)*40 + kg*8);
    }
#pragma unroll
    for (int mi = 0; mi < 4; mi++)
#pragma unroll
      for (int ni = 0; ni < 4; ni++)
        acc[mi][ni] = __builtin_amdgcn_mfma_f32_16x16x32_bf16(af[mi], bfr[ni], acc[mi][ni], 0, 0, 0);
  }
  const int orow0 = bm + wr + kg*4;
  const int ocol0 = bn + wc + fr;
#pragma unroll
  for (int mi = 0; mi < 4; mi++)
#pragma unroll
    for (int ni = 0; ni < 4; ni++)
#pragma unroll
      for (int j = 0; j < 4; j++)
        Cc[(size_t)(orow0 + mi*16 + j)*Nn + ocol0 + ni*16] = acc[mi][ni][j];
}

// ---------------- fused LoRA stage-2 + decay/gates elementwise ----------------
__global__ __launch_bounds__(256) void lora2_kernel(
    const float* __restrict__ d1, const float* __restrict__ a1, const float* __restrict__ ma1,
    const float* __restrict__ mk1, const float* __restrict__ kk1,
    const float* __restrict__ dw2, const float* __restrict__ aw2, const float* __restrict__ maw2,
    const float* __restrict__ mkw2, const float* __restrict__ kkw2,
    const float* __restrict__ td, const float* __restrict__ aaaaa,
    const float* __restrict__ misc_a, const float* __restrict__ misc_k,
    float* __restrict__ k0,                    // in: raw k  out: final k
    float* __restrict__ a_out, float* __restrict__ ew_out, float* __restrict__ kk0_out)
{
  const int j = blockIdx.y*256 + threadIdx.x;
  const int i0 = blockIdx.x*8;
  float accW[8] = {}, accA[8] = {}, accMA[8] = {}, accMK[8] = {}, accKK[8] = {};
  for (int k = 0; k < 64; k++){
    float wv = dw2[(size_t)k*C_ + j];
#pragma unroll
    for (int r = 0; r < 8; r++) accW[r] += d1[(size_t)(i0+r)*64 + k] * wv;
  }
  for (int k = 0; k < 16; k++){
    float w_a  = aw2[(size_t)k*C_ + j];
    float w_ma = maw2[(size_t)k*C_ + j];
    float w_mk = mkw2[(size_t)k*C_ + j];
    float w_kk = kkw2[(size_t)k*C_ + j];
#pragma unroll
    for (int r = 0; r < 8; r++){
      accA[r]  += a1[(size_t)(i0+r)*16 + k] * w_a;
      accMA[r] += ma1[(size_t)(i0+r)*16 + k] * w_ma;
      accMK[r] += mk1[(size_t)(i0+r)*16 + k] * w_mk;
      accKK[r] += kk1[(size_t)(i0+r)*16 + k] * w_kk;
    }
  }
  float tdv = td[j], aav = aaaaa[j], mav = misc_a[j], mkv = misc_k[j];
#pragma unroll
  for (int r = 0; r < 8; r++){
    size_t idx = (size_t)(i0+r)*C_ + j;
    float u  = tdv + accW[r];
    float w  = -log1pf(expf(-u)) - 0.5f;               // -softplus(-u) - 0.5
    float a  = 1.f/(1.f + expf(-(aav + accA[r])));
    float ma = 1.f/(1.f + expf(-(mav + accMA[r])));
    float mk = 1.f/(1.f + expf(-(mkv + accMK[r])));
    float kv = k0[idx];
    kk0_out[idx] = kv + accKK[r];
    float kn = kv * (ma + a*(1.f - ma)) * expf(fminf(w*mk, 0.f));
    k0[idx] = kn;
    a_out[idx] = a;
    ew_out[idx] = expf(w);
  }
}

// ---------------- kk normalize per head + b = kk*a (in-place) ----------------
__global__ __launch_bounds__(256) void kknorm_kernel(float* __restrict__ kk0, float* __restrict__ a_bs){
  const size_t grp = (size_t)blockIdx.x*4 + (threadIdx.x >> 6);
  const int lane = threadIdx.x & 63;
  const size_t idx = grp*64 + lane;
  float kv = kk0[idx];
  float ss = wave64_sum(kv*kv);
  float nrm = fmaxf(sqrtf(ss), 1e-12f);
  float kkn = kv / nrm;
  kk0[idx] = kkn;
  a_bs[idx] = kkn * a_bs[idx];
}

// ---------------- RWKV-7 recurrence: 64 blocks (b,h) x 256 threads ----------------
// Software-pipelined: 4 register step-buffers, loads issued ~3 steps ahead of use.
// VGPR target ~360 (launch_bounds(256,1)); only 4 waves/CU live, occupancy irrelevant.
struct SR { float4 a[4], e[4], k[4], b[4], r[4]; float vt; };

__device__ __forceinline__ void rec_load(SR& s,
    const float* __restrict__ rr, const float* __restrict__ kx, const float* __restrict__ vx,
    const float* __restrict__ ew, const float* __restrict__ kkv, const float* __restrict__ bsv,
    size_t base, int t, int kq16, int v){
  const size_t off = base + (size_t)t*(H_*64);
  const size_t ko = off + kq16;
#pragma unroll
  for (int q = 0; q < 4; q++){
    s.a[q] = *(const float4*)(kkv + ko + 4*q);
    s.e[q] = *(const float4*)(ew  + ko + 4*q);
    s.k[q] = *(const float4*)(kx  + ko + 4*q);
    s.b[q] = *(const float4*)(bsv + ko + 4*q);
    s.r[q] = *(const float4*)(rr  + ko + 4*q);
  }
  s.vt = vx[off + v];
}

__device__ __forceinline__ void rec_cmp(const SR& s, float S[16],
    float* __restrict__ o, size_t base, int t, int v, int kq){
  float sap = 0.f;
#pragma unroll
  for (int q = 0; q < 4; q++){
    sap += s.a[q].x*S[4*q+0]; sap += s.a[q].y*S[4*q+1];
    sap += s.a[q].z*S[4*q+2]; sap += s.a[q].w*S[4*q+3];
  }
  sap += __shfl_xor(sap, 16, 64);
  sap += __shfl_xor(sap, 32, 64);
  const float sa = -sap;            // a_t = -kk
  const float vt = s.vt;
  float op = 0.f;
#pragma unroll
  for (int q = 0; q < 4; q++){
    S[4*q+0] = S[4*q+0]*s.e[q].x + s.k[q].x*vt + s.b[q].x*sa; op += s.r[q].x*S[4*q+0];
    S[4*q+1] = S[4*q+1]*s.e[q].y + s.k[q].y*vt + s.b[q].y*sa; op += s.r[q].y*S[4*q+1];
    S[4*q+2] = S[4*q+2]*s.e[q].z + s.k[q].z*vt + s.b[q].z*sa; op += s.r[q].z*S[4*q+2];
    S[4*q+3] = S[4*q+3]*s.e[q].w + s.k[q].w*vt + s.b[q].w*sa; op += s.r[q].w*S[4*q+3];
  }
  op += __shfl_xor(op, 16, 64);
  op += __shfl_xor(op, 32, 64);
  if (kq == 0) o[base + (size_t)t*(H_*64) + v] = op;
}

__global__ __launch_bounds__(256, 1) void rec_kernel(
    const float* __restrict__ rr, const float* __restrict__ kx,
    const float* __restrict__ vx, const float* __restrict__ ew,
    const float* __restrict__ kkv, const float* __restrict__ bsv,
    const float* __restrict__ s0, float* __restrict__ o, float* __restrict__ sT)
{
  const int bh = blockIdx.x;
  const int b = bh >> 5, h = bh & 31;
  const int wid = threadIdx.x >> 6, lane = threadIdx.x & 63;
  const int v = wid*16 + (lane & 15);
  const int kq = lane >> 4;
  const int kq16 = kq*16;
  float S[16];
  {
    const float* p = s0 + ((size_t)bh*64 + kq16)*64 + v;
#pragma unroll
    for (int i = 0; i < 16; i++) S[i] = p[(size_t)i*64];
  }
  const size_t base = (size_t)b*T_*(H_*64) + (size_t)h*64;

  SR s0r, s1r, s2r, s3r;
  rec_load(s0r, rr, kx, vx, ew, kkv, bsv, base, 0, kq16, v);
  rec_load(s1r, rr, kx, vx, ew, kkv, bsv, base, 1, kq16, v);
  rec_load(s2r, rr, kx, vx, ew, kkv, bsv, base, 2, kq16, v);
#define CLMP(tt) ((tt) < T_ ? (tt) : (T_-1))
  for (int t = 0; t < T_; t += 4){
    rec_load(s3r, rr, kx, vx, ew, kkv, bsv, base, CLMP(t+3), kq16, v);
    rec_cmp(s0r, S, o, base, t+0, v, kq);
    rec_load(s0r, rr, kx, vx, ew, kkv, bsv, base, CLMP(t+4), kq16, v);
    rec_cmp(s1r, S, o, base, t+1, v, kq);
    rec_load(s1r, rr, kx, vx, ew, kkv, bsv, base, CLMP(t+5), kq16, v);
    rec_cmp(s2r, S, o, base, t+2, v, kq);
    rec_load(s2r, rr, kx, vx, ew, kkv, bsv, base, CLMP(t+6), kq16, v);
    rec_cmp(s3r, S, o, base, t+3, v, kq);
  }
#undef CLMP
  float* p = sT + ((size_t)bh*64 + kq16)*64 + v;
#pragma unroll
  for (int i = 0; i < 16; i++) p[(size_t)i*64] = S[i];
}

// ---------------- GroupNorm + faaaa term + *g -> z (bf16) ----------------
__global__ __launch_bounds__(256) void post_kernel(
    const float* __restrict__ o, const float* __restrict__ r, const float* __restrict__ k,
    const float* __restrict__ v, const __hip_bfloat16* __restrict__ g,
    const float* __restrict__ lnw, const float* __restrict__ lnb,
    const float* __restrict__ faaaa, __hip_bfloat16* __restrict__ z_h)
{
  const size_t grp = (size_t)blockIdx.x*4 + (threadIdx.x >> 6);
  const int lane = threadIdx.x & 63;
  const int h = (int)(grp & (H_-1));
  const size_t idx = grp*64 + lane;
  const int ci = h*64 + lane;
  float y = o[idx];
  float mu = wave64_sum(y) * (1.f/64.f);
  float d = y - mu;
  float var = wave64_sum(d*d) * (1.f/64.f);
  float yn = d * rsqrtf(var + 64e-5f) * lnw[ci] + lnb[ci];
  float s = wave64_sum(r[idx]*k[idx]*faaaa[ci]);
  float xo = yn + s*v[idx];
  z_h[idx] = __float2bfloat16(xo * __bfloat162float(g[idx]));
}

// ---------------- x[:, -1] ----------------
__global__ __launch_bounds__(256) void lastx_kernel(const float* __restrict__ x, float* __restrict__ out1){
  int idx = blockIdx.x*256 + threadIdx.x;   // B*C
  int b = idx / C_, c = idx % C_;
  out1[idx] = x[((size_t)b*T_ + (T_-1))*C_ + c];
}

extern "C" void kernel_launch(void* const* d_in, const int* in_sizes, int n_in,
                              void* d_out, int out_size, void* d_ws, size_t ws_size,
                              hipStream_t stream){
  (void)in_sizes; (void)n_in; (void)out_size;
  const float* x      = (const float*)d_in[0];
  const float* shift  = (const float*)d_in[1];
  const float* wkv0   = (const float*)d_in[2];
  const float* maa_x  = (const float*)d_in[3];
  const float* maa_rg = (const float*)d_in[4];
  const float* maa_wa = (const float*)d_in[5];
  const float* maa_k  = (const float*)d_in[6];
  const float* maa_v  = (const float*)d_in[7];
  const float* maa_w1 = (const float*)d_in[8];
  const float* maa_w2 = (const float*)d_in[9];
  const float* tdecay = (const float*)d_in[10];
  const float* dw1    = (const float*)d_in[11];
  const float* dw2    = (const float*)d_in[12];
  const float* faaaa  = (const float*)d_in[13];
  const float* aaaaa  = (const float*)d_in[14];
  const float* aw1    = (const float*)d_in[15];
  const float* aw2    = (const float*)d_in[16];
  const float* kkw1   = (const float*)d_in[17];
  const float* kkw2   = (const float*)d_in[18];
  const float* gw1    = (const float*)d_in[19];
  const float* gw2    = (const float*)d_in[20];
  const float* maw1   = (const float*)d_in[21];
  const float* maw2   = (const float*)d_in[22];
  const float* misc_a = (const float*)d_in[23];
  const float* mkw1   = (const float*)d_in[24];
  const float* mkw2   = (const float*)d_in[25];
  const float* misc_k = (const float*)d_in[26];
  const float* Wr     = (const float*)d_in[27];
  const float* Wk     = (const float*)d_in[28];
  const float* Wv     = (const float*)d_in[29];
  const float* Wo     = (const float*)d_in[30];
  const float* lnw    = (const float*)d_in[31];
  const float* lnb    = (const float*)d_in[32];

  float* out0 = (float*)d_out;                 // [B,T,C]  (also holds o pre-epilogue)
  float* out1 = out0 + BTC_;                   // [B,C]
  float* outS = out1 + (size_t)B_*C_;          // [B,H,N,N]

  // ---- workspace layout (floats) ----
  const size_t SMALL = (size_t)BT_*(128+64+128+16*4);
  const size_t NEEDED = (6*BTC_ + SMALL)*4 + 5*CC_*2;
  if (ws_size < NEEDED) return;   // diagnostic: clean fail instead of OOB fault

  float* ws = (float*)d_ws;
  float* rbuf  = ws;
  float* kbuf  = ws + 1*BTC_;
  float* vbuf  = ws + 2*BTC_;
  float* abuf  = ws + 3*BTC_;   // a -> b_s ; early alias: xx
  float* ewbuf = ws + 4*BTC_;   // exp(w)   ; early alias: xmx
  float* kkbuf = ws + 5*BTC_;   // kk0 -> kk
  float* xx  = abuf;
  float* xmx = ewbuf;
  float* m1  = ws + 6*BTC_;
  float* d1  = m1  + (size_t)BT_*128;
  float* g1  = d1  + (size_t)BT_*64;
  float* a1  = g1  + (size_t)BT_*128;
  float* kk1 = a1  + (size_t)BT_*16;
  float* ma1 = kk1 + (size_t)BT_*16;
  float* mk1 = ma1 + (size_t)BT_*16;
  __hip_bfloat16* hb = (__hip_bfloat16*)(mk1 + (size_t)BT_*16);
  __hip_bfloat16* xrg_h = hb;
  __hip_bfloat16* xwa_h = hb + 1*CC_;
  __hip_bfloat16* xk_h  = hb + 2*CC_;
  __hip_bfloat16* xv_h  = hb + 3*CC_;
  __hip_bfloat16* Wb    = hb + 4*CC_;
  __hip_bfloat16* g_h   = xwa_h;  // xwa_h dead after LoRA stage-1
  __hip_bfloat16* z_h   = xv_h;   // xv_h dead after v GEMM

  dim3 blk(256);

  // token shift + maa stage 1 + mix
  shift_kernel<<<(int)(BTC_/256), blk, 0, stream>>>(x, shift, maa_x, xx, xmx);
  mm_sn<<<BT_/2, blk, 0, stream>>>(xmx, maa_w1, m1, C_, 128, 1);
  mix_kernel<<<dim3(BT_/8, C_/256), blk, 0, stream>>>(m1, maa_w2, x, xx, maa_rg, maa_wa, maa_k, maa_v,
                                                      xrg_h, xwa_h, xk_h, xv_h);
  // LoRA stage 1 (bf16 activations)
  mm_sn_h<<<BT_/4,  blk, 0, stream>>>(xwa_h, dw1,  d1,  C_, 64, 1);
  mm_sn_h<<<BT_/2,  blk, 0, stream>>>(xrg_h, gw1,  g1,  C_, 128, 1);
  mm_sn_h<<<BT_/16, blk, 0, stream>>>(xwa_h, aw1,  a1,  C_, 16, 0);
  mm_sn_h<<<BT_/16, blk, 0, stream>>>(xk_h,  kkw1, kk1, C_, 16, 1);
  mm_sn_h<<<BT_/16, blk, 0, stream>>>(xwa_h, maw1, ma1, C_, 16, 0);
  mm_sn_h<<<BT_/16, blk, 0, stream>>>(xk_h,  mkw1, mk1, C_, 16, 0);
  // g (overwrites xwa_h slot - safe after LoRA1)
  mm_sk_g<<<dim3(BT_/8, C_/256), blk, 0, stream>>>(g1, gw2, g_h, 128);

  // big GEMMs with sequential weight conversion into shared Wb
  f2bf_kernel<<<(int)(CC_/256), blk, 0, stream>>>(Wr, Wb, CC_);
  gemm_bt<<<dim3(BT_/128, C_/128), blk, 0, stream>>>(xrg_h, Wb, rbuf, BT_, C_, C_);
  f2bf_kernel<<<(int)(CC_/256), blk, 0, stream>>>(Wk, Wb, CC_);
  gemm_bt<<<dim3(BT_/128, C_/128), blk, 0, stream>>>(xk_h,  Wb, kbuf, BT_, C_, C_);
  f2bf_kernel<<<(int)(CC_/256), blk, 0, stream>>>(Wv, Wb, CC_);
  gemm_bt<<<dim3(BT_/128, C_/128), blk, 0, stream>>>(xv_h,  Wb, vbuf, BT_, C_, C_);

  // LoRA stage 2 fused + elementwise, then kk normalize
  lora2_kernel<<<dim3(BT_/8, C_/256), blk, 0, stream>>>(d1, a1, ma1, mk1, kk1,
                                                        dw2, aw2, maw2, mkw2, kkw2,
                                                        tdecay, aaaaa, misc_a, misc_k,
                                                        kbuf, abuf, ewbuf, kkbuf);
  kknorm_kernel<<<BT_*H_/4, blk, 0, stream>>>(kkbuf, abuf);

  // recurrence (o written into out0, overwritten by final GEMM later)
  rec_kernel<<<B_*H_, blk, 0, stream>>>(rbuf, kbuf, vbuf, ewbuf, kkbuf, abuf, wkv0, out0, outS);

  // groupnorm + faaaa + gate -> z_h (bf16), final GEMM, last-x copy
  post_kernel<<<BT_*H_/4, blk, 0, stream>>>(out0, rbuf, kbuf, vbuf, g_h, lnw, lnb, faaaa, z_h);
  f2bf_kernel<<<(int)(CC_/256), blk, 0, stream>>>(Wo, Wb, CC_);
  gemm_bt<<<dim3(BT_/128, C_/128), blk, 0, stream>>>(z_h, Wb, out0, BT_, C_, C_);
  lastx_kernel<<<(B_*C_)/256, blk, 0, stream>>>(x, out1);
}

// Round 4
// 1094.844 us; speedup vs baseline: 2.7036x; 1.8932x over previous
//
#include <hip/hip_runtime.h>
#include <hip/hip_bf16.h>
#include <math.h>

// RWKV-7 Tmix forward, MI355X/gfx950.
// B=2 T=1024 C=2048 H=32 N=64. Outputs: xo [B,T,C], x[:,-1] [B,C], S_final [B,H,N,N].

#define B_ 2
#define T_ 1024
#define C_ 2048
#define H_ 32
#define BT_ (B_*T_)
#define BTC_ ((size_t)BT_*C_)
#define CC_ ((size_t)C_*C_)
#define KS_ 8            // split-K factor for stage-1 GEMMs

typedef __bf16 bf16x8 __attribute__((ext_vector_type(8)));
typedef float f32x4 __attribute__((ext_vector_type(4)));

__device__ __forceinline__ float wave64_sum(float v){
#pragma unroll
  for (int d = 1; d < 64; d <<= 1) v += __shfl_xor(v, d, 64);
  return v;
}

// ---------------- fp32 -> bf16 convert ----------------
__global__ __launch_bounds__(256) void f2bf_kernel(const float* __restrict__ in,
                                                   __hip_bfloat16* __restrict__ out, size_t n){
  size_t i = (size_t)blockIdx.x*256 + threadIdx.x;
  if (i < n) out[i] = __float2bfloat16(in[i]);
}

// ---------------- token shift: xx fp32, xmx bf16 ----------------
__global__ __launch_bounds__(256) void shift_kernel(const float* __restrict__ x,
                                                    const float* __restrict__ shift,
                                                    const float* __restrict__ maa_x,
                                                    float* __restrict__ xx, __hip_bfloat16* __restrict__ xmx_h){
  size_t idx = (size_t)blockIdx.x*256 + threadIdx.x;  // over BTC
  int c = (int)(idx % C_);
  size_t bt = idx / C_;
  int t = (int)(bt % T_);
  int b = (int)(bt / T_);
  float xv = x[idx];
  float prev = (t == 0) ? shift[(size_t)b*C_ + c] : x[idx - C_];
  float d = prev - xv;
  xx[idx] = d;
  xmx_h[idx] = __float2bfloat16(xv + d * maa_x[c]);
}

// ---------------- transpose+convert: W[K=2048,Nsrc] fp32 -> rows [row_off..) of Wt[128,2048] bf16 ----------------
__global__ __launch_bounds__(256) void tp_pack(const float* __restrict__ in, __hip_bfloat16* __restrict__ out,
                                               int Nsrc, int row_off){
  __shared__ float tile[32][33];
  const int t = threadIdx.x;
  const int k0 = blockIdx.x*32, n0 = blockIdx.y*32;
  const int tn = t & 31, tk = t >> 5;  // tk 0..7
#pragma unroll
  for (int q = 0; q < 4; q++){
    int ki = tk + 8*q;
    float v = (n0 + tn < Nsrc) ? in[(size_t)(k0+ki)*Nsrc + n0 + tn] : 0.f;
    tile[tn][ki] = v;
  }
  __syncthreads();
#pragma unroll
  for (int q = 0; q < 4; q++){
    int no = tk + 8*q;
    if (n0 + no < Nsrc)
      out[(size_t)(row_off + n0 + no)*2048 + k0 + tn] = __float2bfloat16(tile[no][tn]);
  }
}

// ---------------- split-K skinny MFMA GEMM: parts[z] = A[128rows x KC] * B[128, KC]^T ----------------
__global__ __launch_bounds__(256) void gemm_sk(const __hip_bfloat16* __restrict__ Ah,
                                               const __hip_bfloat16* __restrict__ Bh,
                                               float* __restrict__ parts, int K, int KC){
  __shared__ __bf16 As[128*40];
  __shared__ __bf16 Bs[128*40];
  const int tid = threadIdx.x;
  const int bm = blockIdx.x*128;
  const int z = blockIdx.y;
  const int wid = tid >> 6, lane = tid & 63;
  const int wr = (wid >> 1)*64, wc = (wid & 1)*64;
  const int fr = lane & 15, kg = lane >> 4;
  const int srow = tid >> 2, sk = (tid & 3)*8;
  f32x4 acc[4][4] = {};
  const int kend = z*KC + KC;
  for (int kt = z*KC; kt < kend; kt += 32){
    __syncthreads();
    uint4 a0 = *(const uint4*)(Ah + (size_t)(bm+srow)*K + kt + sk);
    uint4 a1 = *(const uint4*)(Ah + (size_t)(bm+srow+64)*K + kt + sk);
    uint4 b0 = *(const uint4*)(Bh + (size_t)(srow)*K + kt + sk);
    uint4 b1 = *(const uint4*)(Bh + (size_t)(srow+64)*K + kt + sk);
    *(uint4*)(As + srow*40 + sk)      = a0;
    *(uint4*)(As + (srow+64)*40 + sk) = a1;
    *(uint4*)(Bs + srow*40 + sk)      = b0;
    *(uint4*)(Bs + (srow+64)*40 + sk) = b1;
    __syncthreads();
    bf16x8 af[4], bfr[4];
#pragma unroll
    for (int i = 0; i < 4; i++){
      af[i]  = *(const bf16x8*)(As + (wr + i*16 + fr)*40 + kg*8);
      bfr[i] = *(const bf16x8*)(Bs + (wc + i*16 + fr)*40 + kg*8);
    }
#pragma unroll
    for (int mi = 0; mi < 4; mi++)
#pragma unroll
      for (int ni = 0; ni < 4; ni++)
        acc[mi][ni] = __builtin_amdgcn_mfma_f32_16x16x32_bf16(af[mi], bfr[ni], acc[mi][ni], 0, 0, 0);
  }
  float* Cc = parts + (size_t)z*BT_*128;
  const int orow0 = bm + wr + kg*4;
  const int ocol0 = wc + fr;
#pragma unroll
  for (int mi = 0; mi < 4; mi++)
#pragma unroll
    for (int ni = 0; ni < 4; ni++)
#pragma unroll
      for (int j = 0; j < 4; j++)
        Cc[(size_t)(orow0 + mi*16 + j)*128 + ocol0 + ni*16] = acc[mi][ni][j];
}

// ---------------- reduce split-K parts + fused tanh on column range ----------------
__global__ __launch_bounds__(256) void reduce_sk(const float* __restrict__ parts, float* __restrict__ out,
                                                 int tanh_lo, int tanh_hi){
  size_t idx = (size_t)blockIdx.x*256 + threadIdx.x;  // BT*128
  float s = 0.f;
#pragma unroll
  for (int z = 0; z < KS_; z++) s += parts[(size_t)z*BT_*128 + idx];
  int c = (int)(idx & 127);
  if (c >= tanh_lo && c < tanh_hi) s = tanhf(s);
  out[idx] = s;
}

// ---------------- g = tanh'd g1[BT,128] @ gw2[128,C] -> bf16 ----------------
__global__ __launch_bounds__(256) void mm_sk_g(const float* __restrict__ A, const float* __restrict__ W,
                                               __hip_bfloat16* __restrict__ out, int K){
  const int j = blockIdx.y*256 + threadIdx.x;
  const int i0 = blockIdx.x*8;
  float acc[8] = {0,0,0,0,0,0,0,0};
  for (int k = 0; k < K; k++){
    float wv = W[(size_t)k*C_ + j];
#pragma unroll
    for (int r = 0; r < 8; r++) acc[r] += A[(size_t)(i0+r)*K + k] * wv;
  }
#pragma unroll
  for (int r = 0; r < 8; r++) out[(size_t)(i0+r)*C_ + j] = __float2bfloat16(acc[r]);
}

// ---------------- maa einsum + mix -> bf16 xrg/xwa/xk/xv ----------------
__global__ __launch_bounds__(256) void mix_kernel(
    const float* __restrict__ m1, const float* __restrict__ w2,
    const float* __restrict__ x, const float* __restrict__ xx,
    const float* __restrict__ maa_rg, const float* __restrict__ maa_wa,
    const float* __restrict__ maa_k, const float* __restrict__ maa_v,
    __hip_bfloat16* __restrict__ xrg_h, __hip_bfloat16* __restrict__ xwa_h,
    __hip_bfloat16* __restrict__ xk_h, __hip_bfloat16* __restrict__ xv_h)
{
  const int j = blockIdx.y*256 + threadIdx.x;
  const int i0 = blockIdx.x*8;
  float acc[4][8] = {};
#pragma unroll
  for (int f = 0; f < 4; f++){
    for (int d = 0; d < 32; d++){
      float wv = w2[((size_t)f*32 + d)*C_ + j];
#pragma unroll
      for (int r = 0; r < 8; r++)
        acc[f][r] += m1[(size_t)(i0+r)*128 + f*32 + d] * wv;
    }
  }
  float mrg_ = maa_rg[j], mwa_ = maa_wa[j], mk_ = maa_k[j], mv_ = maa_v[j];
#pragma unroll
  for (int r = 0; r < 8; r++){
    size_t idx = (size_t)(i0+r)*C_ + j;
    float xval = x[idx], xxv = xx[idx];
    xrg_h[idx] = __float2bfloat16(xval + xxv*(mrg_ + acc[0][r]));
    xwa_h[idx] = __float2bfloat16(xval + xxv*(mwa_ + acc[1][r]));
    xk_h[idx]  = __float2bfloat16(xval + xxv*(mk_  + acc[2][r]));
    xv_h[idx]  = __float2bfloat16(xval + xxv*(mv_  + acc[3][r]));
  }
}

// ---------------- bf16 MFMA GEMM: C[M,N] = A[M,K] * B[N,K]^T (fp32 out) ----------------
__global__ __launch_bounds__(256) void gemm_bt(const __hip_bfloat16* __restrict__ Ah,
                                               const __hip_bfloat16* __restrict__ Bh,
                                               float* __restrict__ Cc, int M, int Nn, int K){
  __shared__ __bf16 As[128*40];
  __shared__ __bf16 Bs[128*40];
  const int tid = threadIdx.x;
  const int bm = blockIdx.x*128, bn = blockIdx.y*128;
  const int wid = tid >> 6, lane = tid & 63;
  const int wr = (wid >> 1)*64, wc = (wid & 1)*64;
  const int fr = lane & 15, kg = lane >> 4;
  const int srow = tid >> 2, sk = (tid & 3)*8;
  f32x4 acc[4][4] = {};
  for (int kt = 0; kt < K; kt += 32){
    __syncthreads();
    uint4 a0 = *(const uint4*)(Ah + (size_t)(bm+srow)*K + kt + sk);
    uint4 a1 = *(const uint4*)(Ah + (size_t)(bm+srow+64)*K + kt + sk);
    uint4 b0 = *(const uint4*)(Bh + (size_t)(bn+srow)*K + kt + sk);
    uint4 b1 = *(const uint4*)(Bh + (size_t)(bn+srow+64)*K + kt + sk);
    *(uint4*)(As + srow*40 + sk)      = a0;
    *(uint4*)(As + (srow+64)*40 + sk) = a1;
    *(uint4*)(Bs + srow*40 + sk)      = b0;
    *(uint4*)(Bs + (srow+64)*40 + sk) = b1;
    __syncthreads();
    bf16x8 af[4], bfr[4];
#pragma unroll
    for (int i = 0; i < 4; i++){
      af[i]  = *(const bf16x8*)(As + (wr + i*16 + fr)*40 + kg*8);
      bfr[i] = *(const bf16x8*)(Bs + (wc + i*16 + fr)*40 + kg*8);
    }
#pragma unroll
    for (int mi = 0; mi < 4; mi++)
#pragma unroll
      for (int ni = 0; ni < 4; ni++)
        acc[mi][ni] = __builtin_amdgcn_mfma_f32_16x16x32_bf16(af[mi], bfr[ni], acc[mi][ni], 0, 0, 0);
  }
  const int orow0 = bm + wr + kg*4;
  const int ocol0 = bn + wc + fr;
#pragma unroll
  for (int mi = 0; mi < 4; mi++)
#pragma unroll
    for (int ni = 0; ni < 4; ni++)
#pragma unroll
      for (int j = 0; j < 4; j++)
        Cc[(size_t)(orow0 + mi*16 + j)*Nn + ocol0 + ni*16] = acc[mi][ni][j];
}

// ---------------- fused LoRA stage-2 + decay/gates elementwise ----------------
// wa1[BT,128]: cols 0..63 = tanh(d1), 64..79 = a1, 80..95 = ma1
// k1c[BT,128]: cols 0..15 = tanh(kk1), 16..31 = mk1
__global__ __launch_bounds__(256) void lora2_kernel(
    const float* __restrict__ wa1, const float* __restrict__ k1c,
    const float* __restrict__ dw2, const float* __restrict__ aw2, const float* __restrict__ maw2,
    const float* __restrict__ mkw2, const float* __restrict__ kkw2,
    const float* __restrict__ td, const float* __restrict__ aaaaa,
    const float* __restrict__ misc_a, const float* __restrict__ misc_k,
    float* __restrict__ k0,                    // in: raw k  out: final k
    float* __restrict__ a_out, float* __restrict__ ew_out, float* __restrict__ kk0_out)
{
  const int j = blockIdx.y*256 + threadIdx.x;
  const int i0 = blockIdx.x*8;
  float accW[8] = {}, accA[8] = {}, accMA[8] = {}, accMK[8] = {}, accKK[8] = {};
  for (int k = 0; k < 64; k++){
    float wv = dw2[(size_t)k*C_ + j];
#pragma unroll
    for (int r = 0; r < 8; r++) accW[r] += wa1[(size_t)(i0+r)*128 + k] * wv;
  }
  for (int k = 0; k < 16; k++){
    float w_a  = aw2[(size_t)k*C_ + j];
    float w_ma = maw2[(size_t)k*C_ + j];
    float w_mk = mkw2[(size_t)k*C_ + j];
    float w_kk = kkw2[(size_t)k*C_ + j];
#pragma unroll
    for (int r = 0; r < 8; r++){
      accA[r]  += wa1[(size_t)(i0+r)*128 + 64 + k] * w_a;
      accMA[r] += wa1[(size_t)(i0+r)*128 + 80 + k] * w_ma;
      accKK[r] += k1c[(size_t)(i0+r)*128 + k] * w_kk;
      accMK[r] += k1c[(size_t)(i0+r)*128 + 16 + k] * w_mk;
    }
  }
  float tdv = td[j], aav = aaaaa[j], mav = misc_a[j], mkv = misc_k[j];
#pragma unroll
  for (int r = 0; r < 8; r++){
    size_t idx = (size_t)(i0+r)*C_ + j;
    float u  = tdv + accW[r];
    float w  = -log1pf(expf(-u)) - 0.5f;               // -softplus(-u) - 0.5
    float a  = 1.f/(1.f + expf(-(aav + accA[r])));
    float ma = 1.f/(1.f + expf(-(mav + accMA[r])));
    float mk = 1.f/(1.f + expf(-(mkv + accMK[r])));
    float kv = k0[idx];
    kk0_out[idx] = kv + accKK[r];
    float kn = kv * (ma + a*(1.f - ma)) * expf(fminf(w*mk, 0.f));
    k0[idx] = kn;
    a_out[idx] = a;
    ew_out[idx] = expf(w);
  }
}

// ---------------- kk normalize per head + b = kk*a (in-place) ----------------
__global__ __launch_bounds__(256) void kknorm_kernel(float* __restrict__ kk0, float* __restrict__ a_bs){
  const size_t grp = (size_t)blockIdx.x*4 + (threadIdx.x >> 6);
  const int lane = threadIdx.x & 63;
  const size_t idx = grp*64 + lane;
  float kv = kk0[idx];
  float ss = wave64_sum(kv*kv);
  float nrm = fmaxf(sqrtf(ss), 1e-12f);
  float kkn = kv / nrm;
  kk0[idx] = kkn;
  a_bs[idx] = kkn * a_bs[idx];
}

// ---------------- RWKV-7 recurrence: 256 blocks x 64 threads (1 wave/block -> all CUs) ----------------
// 4-deep register pipeline; OOB prefetches (t+4..t+6 past T) land in allocated pad - never consumed.
struct SR { float4 a[4], e[4], k[4], b[4], r[4]; float vt; };

__device__ __forceinline__ void rec_load(SR& s,
    const float* __restrict__ rr, const float* __restrict__ kx, const float* __restrict__ vx,
    const float* __restrict__ ew, const float* __restrict__ kkv, const float* __restrict__ bsv,
    size_t base, int t, int kq16, int v){
  const size_t off = base + (size_t)t*(H_*64);
  const size_t ko = off + kq16;
#pragma unroll
  for (int q = 0; q < 4; q++){
    s.a[q] = *(const float4*)(kkv + ko + 4*q);
    s.e[q] = *(const float4*)(ew  + ko + 4*q);
    s.k[q] = *(const float4*)(kx  + ko + 4*q);
    s.b[q] = *(const float4*)(bsv + ko + 4*q);
    s.r[q] = *(const float4*)(rr  + ko + 4*q);
  }
  s.vt = vx[off + v];
}

__device__ __forceinline__ void rec_cmp(const SR& s, float S[16],
    float* __restrict__ o, size_t base, int t, int v, int kq){
  float sap = 0.f;
#pragma unroll
  for (int q = 0; q < 4; q++){
    sap += s.a[q].x*S[4*q+0]; sap += s.a[q].y*S[4*q+1];
    sap += s.a[q].z*S[4*q+2]; sap += s.a[q].w*S[4*q+3];
  }
  sap += __shfl_xor(sap, 16, 64);
  sap += __shfl_xor(sap, 32, 64);
  const float sa = -sap;            // a_t = -kk
  const float vt = s.vt;
  float op = 0.f;
#pragma unroll
  for (int q = 0; q < 4; q++){
    S[4*q+0] = S[4*q+0]*s.e[q].x + s.k[q].x*vt + s.b[q].x*sa; op += s.r[q].x*S[4*q+0];
    S[4*q+1] = S[4*q+1]*s.e[q].y + s.k[q].y*vt + s.b[q].y*sa; op += s.r[q].y*S[4*q+1];
    S[4*q+2] = S[4*q+2]*s.e[q].z + s.k[q].z*vt + s.b[q].z*sa; op += s.r[q].z*S[4*q+2];
    S[4*q+3] = S[4*q+3]*s.e[q].w + s.k[q].w*vt + s.b[q].w*sa; op += s.r[q].w*S[4*q+3];
  }
  op += __shfl_xor(op, 16, 64);
  op += __shfl_xor(op, 32, 64);
  if (kq == 0) o[base + (size_t)t*(H_*64) + v] = op;
}

__global__ __launch_bounds__(64, 1) void rec_kernel(
    const float* __restrict__ rr, const float* __restrict__ kx,
    const float* __restrict__ vx, const float* __restrict__ ew,
    const float* __restrict__ kkv, const float* __restrict__ bsv,
    const float* __restrict__ s0, float* __restrict__ o, float* __restrict__ sT)
{
  const int bh = blockIdx.x >> 2;
  const int wid = blockIdx.x & 3;
  const int b = bh >> 5, h = bh & 31;
  const int lane = threadIdx.x;
  const int v = wid*16 + (lane & 15);
  const int kq = lane >> 4;
  const int kq16 = kq*16;
  float S[16];
  {
    const float* p = s0 + ((size_t)bh*64 + kq16)*64 + v;
#pragma unroll
    for (int i = 0; i < 16; i++) S[i] = p[(size_t)i*64];
  }
  const size_t base = (size_t)b*T_*(H_*64) + (size_t)h*64;

  SR s0r, s1r, s2r, s3r;
  rec_load(s0r, rr, kx, vx, ew, kkv, bsv, base, 0, kq16, v);
  rec_load(s1r, rr, kx, vx, ew, kkv, bsv, base, 1, kq16, v);
  rec_load(s2r, rr, kx, vx, ew, kkv, bsv, base, 2, kq16, v);
  for (int t = 0; t < T_; t += 4){
    rec_load(s3r, rr, kx, vx, ew, kkv, bsv, base, t+3, kq16, v);
    rec_cmp(s0r, S, o, base, t+0, v, kq);
    rec_load(s0r, rr, kx, vx, ew, kkv, bsv, base, t+4, kq16, v);
    rec_cmp(s1r, S, o, base, t+1, v, kq);
    rec_load(s1r, rr, kx, vx, ew, kkv, bsv, base, t+5, kq16, v);
    rec_cmp(s2r, S, o, base, t+2, v, kq);
    rec_load(s2r, rr, kx, vx, ew, kkv, bsv, base, t+6, kq16, v);
    rec_cmp(s3r, S, o, base, t+3, v, kq);
  }
  float* p = sT + ((size_t)bh*64 + kq16)*64 + v;
#pragma unroll
  for (int i = 0; i < 16; i++) p[(size_t)i*64] = S[i];
}

// ---------------- GroupNorm + faaaa term + *g -> z (bf16) ----------------
__global__ __launch_bounds__(256) void post_kernel(
    const float* __restrict__ o, const float* __restrict__ r, const float* __restrict__ k,
    const float* __restrict__ v, const __hip_bfloat16* __restrict__ g,
    const float* __restrict__ lnw, const float* __restrict__ lnb,
    const float* __restrict__ faaaa, __hip_bfloat16* __restrict__ z_h)
{
  const size_t grp = (size_t)blockIdx.x*4 + (threadIdx.x >> 6);
  const int lane = threadIdx.x & 63;
  const int h = (int)(grp & (H_-1));
  const size_t idx = grp*64 + lane;
  const int ci = h*64 + lane;
  float y = o[idx];
  float mu = wave64_sum(y) * (1.f/64.f);
  float d = y - mu;
  float var = wave64_sum(d*d) * (1.f/64.f);
  float yn = d * rsqrtf(var + 64e-5f) * lnw[ci] + lnb[ci];
  float s = wave64_sum(r[idx]*k[idx]*faaaa[ci]);
  float xo = yn + s*v[idx];
  z_h[idx] = __float2bfloat16(xo * __bfloat162float(g[idx]));
}

// ---------------- x[:, -1] ----------------
__global__ __launch_bounds__(256) void lastx_kernel(const float* __restrict__ x, float* __restrict__ out1){
  int idx = blockIdx.x*256 + threadIdx.x;   // B*C
  int b = idx / C_, c = idx % C_;
  out1[idx] = x[((size_t)b*T_ + (T_-1))*C_ + c];
}

extern "C" void kernel_launch(void* const* d_in, const int* in_sizes, int n_in,
                              void* d_out, int out_size, void* d_ws, size_t ws_size,
                              hipStream_t stream){
  (void)in_sizes; (void)n_in; (void)out_size;
  const float* x      = (const float*)d_in[0];
  const float* shift  = (const float*)d_in[1];
  const float* wkv0   = (const float*)d_in[2];
  const float* maa_x  = (const float*)d_in[3];
  const float* maa_rg = (const float*)d_in[4];
  const float* maa_wa = (const float*)d_in[5];
  const float* maa_k  = (const float*)d_in[6];
  const float* maa_v  = (const float*)d_in[7];
  const float* maa_w1 = (const float*)d_in[8];
  const float* maa_w2 = (const float*)d_in[9];
  const float* tdecay = (const float*)d_in[10];
  const float* dw1    = (const float*)d_in[11];
  const float* dw2    = (const float*)d_in[12];
  const float* faaaa  = (const float*)d_in[13];
  const float* aaaaa  = (const float*)d_in[14];
  const float* aw1    = (const float*)d_in[15];
  const float* aw2    = (const float*)d_in[16];
  const float* kkw1   = (const float*)d_in[17];
  const float* kkw2   = (const float*)d_in[18];
  const float* gw1    = (const float*)d_in[19];
  const float* gw2    = (const float*)d_in[20];
  const float* maw1   = (const float*)d_in[21];
  const float* maw2   = (const float*)d_in[22];
  const float* misc_a = (const float*)d_in[23];
  const float* mkw1   = (const float*)d_in[24];
  const float* mkw2   = (const float*)d_in[25];
  const float* misc_k = (const float*)d_in[26];
  const float* Wr     = (const float*)d_in[27];
  const float* Wk     = (const float*)d_in[28];
  const float* Wv     = (const float*)d_in[29];
  const float* Wo     = (const float*)d_in[30];
  const float* lnw    = (const float*)d_in[31];
  const float* lnb    = (const float*)d_in[32];

  float* out0 = (float*)d_out;                 // [B,T,C]  (also holds o pre-epilogue)
  float* out1 = out0 + BTC_;                   // [B,C]
  float* outS = out1 + (size_t)B_*C_;          // [B,H,N,N]

  // ---- workspace layout ----
  // fp32: rbuf kbuf vbuf abuf ewbuf kkbuf (6*BTC) | wa1 g1f k1c (3*BT*128)
  // bf16: xrg_h | xwa_h(->g_h) | xk_h | xv_h(->xmx_h,->z_h) | Wb (5*CC) | WtB (4*128*2048)
  // aliases: parts(split-K, 8*BT*128 fp32) = rbuf ; m1f = vbuf
  const size_t NEEDED = (6*BTC_ + (size_t)3*BT_*128)*4 + 5*CC_*2 + (size_t)4*128*2048*2;
  if (ws_size < NEEDED) return;

  float* ws = (float*)d_ws;
  float* rbuf  = ws;
  float* kbuf  = ws + 1*BTC_;
  float* vbuf  = ws + 2*BTC_;
  float* abuf  = ws + 3*BTC_;   // a -> b_s ; early alias: xx
  float* ewbuf = ws + 4*BTC_;   // exp(w)
  float* kkbuf = ws + 5*BTC_;   // kk0 -> kk
  float* xx    = abuf;
  float* wa1   = ws + 6*BTC_;                    // [BT,128]
  float* g1f   = wa1 + (size_t)BT_*128;          // [BT,128]
  float* k1c   = g1f + (size_t)BT_*128;          // [BT,128]
  float* parts = rbuf;                           // [KS][BT,128] = 8MB < 16MB
  float* m1f   = vbuf;                           // [BT,128]
  __hip_bfloat16* hb = (__hip_bfloat16*)(k1c + (size_t)BT_*128);
  __hip_bfloat16* xrg_h = hb;
  __hip_bfloat16* xwa_h = hb + 1*CC_;
  __hip_bfloat16* xk_h  = hb + 2*CC_;
  __hip_bfloat16* xv_h  = hb + 3*CC_;
  __hip_bfloat16* Wb    = hb + 4*CC_;
  __hip_bfloat16* WtB   = hb + 5*CC_;            // 4 x [128,2048]
  __hip_bfloat16* Wt_m  = WtB;
  __hip_bfloat16* Wt_wa = WtB + (size_t)128*2048;
  __hip_bfloat16* Wt_g  = WtB + (size_t)2*128*2048;
  __hip_bfloat16* Wt_k  = WtB + (size_t)3*128*2048;
  __hip_bfloat16* xmx_h = xv_h;   // consumed by m1 GEMM before mix writes xv_h
  __hip_bfloat16* g_h   = xwa_h;  // xwa_h dead after its stage-1 GEMM
  __hip_bfloat16* z_h   = xv_h;   // xv_h dead after v GEMM

  dim3 blk(256);
  const int KC = C_/KS_;   // 256

  // zero the packed-weight region (covers zero-padding rows)
  hipMemsetAsync(WtB, 0, (size_t)4*128*2048*2, stream);
  // pack stage-1 weights: transpose+convert into [128,2048] bf16
  tp_pack<<<dim3(64,4), blk, 0, stream>>>(maa_w1, Wt_m, 128, 0);
  tp_pack<<<dim3(64,2), blk, 0, stream>>>(dw1,  Wt_wa, 64, 0);
  tp_pack<<<dim3(64,1), blk, 0, stream>>>(aw1,  Wt_wa, 16, 64);
  tp_pack<<<dim3(64,1), blk, 0, stream>>>(maw1, Wt_wa, 16, 80);
  tp_pack<<<dim3(64,4), blk, 0, stream>>>(gw1,  Wt_g, 128, 0);
  tp_pack<<<dim3(64,1), blk, 0, stream>>>(kkw1, Wt_k, 16, 0);
  tp_pack<<<dim3(64,1), blk, 0, stream>>>(mkw1, Wt_k, 16, 16);

  // token shift (xx fp32 into abuf, xmx bf16 into xv_h slot)
  shift_kernel<<<(int)(BTC_/256), blk, 0, stream>>>(x, shift, maa_x, xx, xmx_h);

  // m1 = tanh(xmx @ maa_w1): split-K MFMA + reduce
  gemm_sk<<<dim3(BT_/128, KS_), blk, 0, stream>>>(xmx_h, Wt_m, parts, C_, KC);
  reduce_sk<<<BT_*128/256, blk, 0, stream>>>(parts, m1f, 0, 128);

  // mix -> xrg/xwa/xk/xv bf16 (overwrites xmx_h slot with xv_h)
  mix_kernel<<<dim3(BT_/8, C_/256), blk, 0, stream>>>(m1f, maa_w2, x, xx, maa_rg, maa_wa, maa_k, maa_v,
                                                      xrg_h, xwa_h, xk_h, xv_h);
  // stage-1 LoRA GEMMs
  gemm_sk<<<dim3(BT_/128, KS_), blk, 0, stream>>>(xwa_h, Wt_wa, parts, C_, KC);
  reduce_sk<<<BT_*128/256, blk, 0, stream>>>(parts, wa1, 0, 64);      // tanh on d1 cols
  gemm_sk<<<dim3(BT_/128, KS_), blk, 0, stream>>>(xrg_h, Wt_g, parts, C_, KC);
  reduce_sk<<<BT_*128/256, blk, 0, stream>>>(parts, g1f, 0, 128);     // tanh all
  gemm_sk<<<dim3(BT_/128, KS_), blk, 0, stream>>>(xk_h, Wt_k, parts, C_, KC);
  reduce_sk<<<BT_*128/256, blk, 0, stream>>>(parts, k1c, 0, 16);      // tanh on kk1 cols

  // g (overwrites xwa_h slot)
  mm_sk_g<<<dim3(BT_/8, C_/256), blk, 0, stream>>>(g1f, gw2, g_h, 128);

  // big GEMMs with sequential weight conversion into shared Wb (r-GEMM overwrites parts)
  f2bf_kernel<<<(int)(CC_/256), blk, 0, stream>>>(Wr, Wb, CC_);
  gemm_bt<<<dim3(BT_/128, C_/128), blk, 0, stream>>>(xrg_h, Wb, rbuf, BT_, C_, C_);
  f2bf_kernel<<<(int)(CC_/256), blk, 0, stream>>>(Wk, Wb, CC_);
  gemm_bt<<<dim3(BT_/128, C_/128), blk, 0, stream>>>(xk_h,  Wb, kbuf, BT_, C_, C_);
  f2bf_kernel<<<(int)(CC_/256), blk, 0, stream>>>(Wv, Wb, CC_);
  gemm_bt<<<dim3(BT_/128, C_/128), blk, 0, stream>>>(xv_h,  Wb, vbuf, BT_, C_, C_);

  // LoRA stage 2 fused + elementwise, then kk normalize
  lora2_kernel<<<dim3(BT_/8, C_/256), blk, 0, stream>>>(wa1, k1c,
                                                        dw2, aw2, maw2, mkw2, kkw2,
                                                        tdecay, aaaaa, misc_a, misc_k,
                                                        kbuf, abuf, ewbuf, kkbuf);
  kknorm_kernel<<<BT_*H_/4, blk, 0, stream>>>(kkbuf, abuf);

  // recurrence: 256 blocks x 64 threads (o into out0, overwritten by final GEMM)
  rec_kernel<<<B_*H_*4, dim3(64), 0, stream>>>(rbuf, kbuf, vbuf, ewbuf, kkbuf, abuf, wkv0, out0, outS);

  // groupnorm + faaaa + gate -> z_h (bf16), final GEMM, last-x copy
  post_kernel<<<BT_*H_/4, blk, 0, stream>>>(out0, rbuf, kbuf, vbuf, g_h, lnw, lnb, faaaa, z_h);
  f2bf_kernel<<<(int)(CC_/256), blk, 0, stream>>>(Wo, Wb, CC_);
  gemm_bt<<<dim3(BT_/128, C_/128), blk, 0, stream>>>(z_h, Wb, out0, BT_, C_, C_);
  lastx_kernel<<<(B_*C_)/256, blk, 0, stream>>>(x, out1);
}